// Round 1
// baseline (372.088 us; speedup 1.0000x reference)
//
#include <hip/hip_runtime.h>
#include <stdint.h>

typedef unsigned short ushort_t;
typedef __attribute__((ext_vector_type(8))) short bf16x8;   // 8 bf16 in 4 VGPRs
typedef __attribute__((ext_vector_type(4))) float f32x4;

__device__ __forceinline__ float bf2f(unsigned short u) {
  return __uint_as_float(((unsigned)u) << 16);
}
__device__ __forceinline__ unsigned short f2bf(float f) {
  unsigned u = __float_as_uint(f);
  u += 0x7FFFu + ((u >> 16) & 1u);   // RNE
  return (unsigned short)(u >> 16);
}

__device__ __forceinline__ void gload_lds16(const ushort_t* g, ushort_t* l) {
  __builtin_amdgcn_global_load_lds(
      (__attribute__((address_space(1))) void*)(void*)g,
      (__attribute__((address_space(3))) void*)(void*)l, 16, 0, 0);
}

// ---------------- pack weights: Wcat (1536x1024 bf16), Ww (1024x512 bf16), bias_cat ----
__global__ void pack_weights(const float* __restrict__ g_w, const float* __restrict__ th_w,
                             const float* __restrict__ ph_w, const float* __restrict__ W_w,
                             const float* __restrict__ g_b, const float* __restrict__ th_b,
                             const float* __restrict__ ph_b,
                             ushort_t* __restrict__ Wcat, ushort_t* __restrict__ Ww,
                             float* __restrict__ bias_cat) {
  int i = blockIdx.x * 256 + threadIdx.x;
  if (i < 1536 * 1024) {
    int r = i >> 10;
    float val;
    if (r < 512)        val = g_w[i];
    else if (r < 1024)  val = th_w[i - 512 * 1024];
    else                val = ph_w[i - 1024 * 1024];
    Wcat[i] = f2bf(val);
  } else if (i < 1536 * 1024 + 512 * 1024) {
    int j = i - 1536 * 1024;
    Ww[j] = f2bf(W_w[j]);   // W_w is (1024, 512) row-major == B^T layout for GEMM4
  }
  if (i < 512)        bias_cat[i] = g_b[i];
  else if (i < 1024)  bias_cat[i] = th_b[i - 512];
  else if (i < 1536)  bias_cat[i] = ph_b[i - 1024];
}

// ---------------- cast v (fp32) -> bf16 --------------------------------------------
__global__ void cast_f32_bf16(const float* __restrict__ in, ushort_t* __restrict__ out) {
  size_t i = ((size_t)blockIdx.x * 256 + threadIdx.x) * 4;
  float4 f = *(const float4*)(in + i);
  ushort_t o0 = f2bf(f.x), o1 = f2bf(f.y), o2 = f2bf(f.z), o3 = f2bf(f.w);
  // pack as two u32 stores (8B)
  unsigned lo = (unsigned)o0 | ((unsigned)o1 << 16);
  unsigned hi = (unsigned)o2 | ((unsigned)o3 << 16);
  *(uint2*)(out + i) = make_uint2(lo, hi);
}

// ---------------- LDS tile transpose: out[b][j][n] = P[b*4096+n][coff+j] ------------
__global__ void transpose_cols(const ushort_t* __restrict__ P, int coff,
                               ushort_t* __restrict__ out) {
  __shared__ ushort_t t[32][33];
  int b = blockIdx.z;
  int n0 = blockIdx.x * 32, j0 = blockIdx.y * 32;
  const ushort_t* Pb = P + (size_t)b * 4096 * 1536 + coff;
  for (int r = threadIdx.y; r < 32; r += 8)
    t[r][threadIdx.x] = Pb[(size_t)(n0 + r) * 1536 + j0 + threadIdx.x];
  __syncthreads();
  ushort_t* ob = out + (size_t)b * 512 * 4096;
  for (int r = threadIdx.y; r < 32; r += 8)
    ob[(size_t)(j0 + r) * 4096 + n0 + threadIdx.x] = t[threadIdx.x][r];
}

// ---------------- bf16 GEMM: C[m][n] = alpha * sum_k A[m][k]*BT[n][k] (+ bias[n]) ---
// 256 threads = 4 waves in 2x2 grid; per-wave (BM/2)x(BN/2) via 16x16x32 MFMA frags.
template <int BM, int BN, bool BIAS>
__global__ __launch_bounds__(256) void gemm_bt(
    const ushort_t* __restrict__ A, const ushort_t* __restrict__ B,
    ushort_t* __restrict__ C, const float* __restrict__ bias,
    int K, int lda, int ldb, int ldc, long sA, long sB, long sC, float alpha) {
  constexpr int FR_M = BM / 32, FR_N = BN / 32;
  __shared__ ushort_t As[BM * 64];
  __shared__ ushort_t Bs[BN * 64];
  const int tid = threadIdx.x;
  const int lane = tid & 63;
  const int wm = tid >> 7;         // wave row (0..1)
  const int wn = (tid >> 6) & 1;   // wave col (0..1)
  const long b = blockIdx.z;
  A += b * sA; B += b * sB; C += b * sC;
  const int tm0 = blockIdx.x * BM, tn0 = blockIdx.y * BN;

  f32x4 acc[FR_M][FR_N] = {};

  for (int kt = 0; kt < K; kt += 64) {
#pragma unroll
    for (int it = 0; it < BM / 32; ++it) {
      int g = it * 256 + tid;
      gload_lds16(A + (long)(tm0 + (g >> 3)) * lda + kt + (g & 7) * 8, &As[g * 8]);
    }
#pragma unroll
    for (int it = 0; it < BN / 32; ++it) {
      int g = it * 256 + tid;
      gload_lds16(B + (long)(tn0 + (g >> 3)) * ldb + kt + (g & 7) * 8, &Bs[g * 8]);
    }
    __syncthreads();   // drains vmcnt before barrier
#pragma unroll
    for (int kk = 0; kk < 2; ++kk) {
      bf16x8 af[FR_M], bfr[FR_N];
#pragma unroll
      for (int m = 0; m < FR_M; ++m)
        af[m] = *(const bf16x8*)&As[(wm * (BM / 2) + m * 16 + (lane & 15)) * 64 +
                                    kk * 32 + (lane >> 4) * 8];
#pragma unroll
      for (int n = 0; n < FR_N; ++n)
        bfr[n] = *(const bf16x8*)&Bs[(wn * (BN / 2) + n * 16 + (lane & 15)) * 64 +
                                     kk * 32 + (lane >> 4) * 8];
#pragma unroll
      for (int m = 0; m < FR_M; ++m)
#pragma unroll
        for (int n = 0; n < FR_N; ++n)
          acc[m][n] = __builtin_amdgcn_mfma_f32_16x16x32_bf16(af[m], bfr[n], acc[m][n], 0, 0, 0);
    }
    __syncthreads();
  }

#pragma unroll
  for (int m = 0; m < FR_M; ++m) {
#pragma unroll
    for (int n = 0; n < FR_N; ++n) {
      const int col = tn0 + wn * (BN / 2) + n * 16 + (lane & 15);
      const float bv = BIAS ? bias[col] : 0.0f;
#pragma unroll
      for (int r = 0; r < 4; ++r) {
        const int row = tm0 + wm * (BM / 2) + m * 16 + (lane >> 4) * 4 + r;
        C[(long)row * ldc + col] = f2bf(alpha * acc[m][n][r] + bv);
      }
    }
  }
}

// ---------------- BN stats: per-channel sum / sumsq over 16384 rows -----------------
__global__ void bn_stats(const ushort_t* __restrict__ Wy, float* __restrict__ sums) {
  int c = blockIdx.x * 256 + threadIdx.x;   // 4 x 256 = 1024 channels
  int r0 = blockIdx.y * 256;
  float s = 0.f, s2 = 0.f;
  for (int r = 0; r < 256; ++r) {
    float val = bf2f(Wy[(size_t)(r0 + r) * 1024 + c]);
    s += val; s2 += val * val;
  }
  atomicAdd(&sums[c], s);
  atomicAdd(&sums[1024 + c], s2);
}

__global__ void bn_finalize(const float* __restrict__ sums, const float* __restrict__ gamma,
                            const float* __restrict__ beta, float* __restrict__ scsh) {
  int c = blockIdx.x * 256 + threadIdx.x;
  float mean = sums[c] * (1.0f / 16384.0f);
  float var = sums[1024 + c] * (1.0f / 16384.0f) - mean * mean;
  float sc = gamma[c] * rsqrtf(var + 1e-5f);
  scsh[c] = sc;
  scsh[1024 + c] = beta[c] - mean * sc;
}

// ---------------- apply BN + residual: out = Wy*scale + shift + v -------------------
__global__ void bn_apply(const ushort_t* __restrict__ Wy, const float* __restrict__ v,
                         const float* __restrict__ scsh, float* __restrict__ out) {
  size_t i = ((size_t)blockIdx.x * 256 + threadIdx.x) * 8;
  int c0 = (int)(i & 1023);
  bf16x8 w = *(const bf16x8*)(Wy + i);
  float4 v0 = *(const float4*)(v + i);
  float4 v1 = *(const float4*)(v + i + 4);
  float4 sc0 = *(const float4*)(scsh + c0);
  float4 sc1 = *(const float4*)(scsh + c0 + 4);
  float4 sh0 = *(const float4*)(scsh + 1024 + c0);
  float4 sh1 = *(const float4*)(scsh + 1024 + c0 + 4);
  float4 o0, o1;
  o0.x = bf2f((unsigned short)w[0]) * sc0.x + sh0.x + v0.x;
  o0.y = bf2f((unsigned short)w[1]) * sc0.y + sh0.y + v0.y;
  o0.z = bf2f((unsigned short)w[2]) * sc0.z + sh0.z + v0.z;
  o0.w = bf2f((unsigned short)w[3]) * sc0.w + sh0.w + v0.w;
  o1.x = bf2f((unsigned short)w[4]) * sc1.x + sh1.x + v1.x;
  o1.y = bf2f((unsigned short)w[5]) * sc1.y + sh1.y + v1.y;
  o1.z = bf2f((unsigned short)w[6]) * sc1.z + sh1.z + v1.z;
  o1.w = bf2f((unsigned short)w[7]) * sc1.w + sh1.w + v1.w;
  *(float4*)(out + i) = o0;
  *(float4*)(out + i + 4) = o1;
}

extern "C" void kernel_launch(void* const* d_in, const int* in_sizes, int n_in,
                              void* d_out, int out_size, void* d_ws, size_t ws_size,
                              hipStream_t stream) {
  const float* v     = (const float*)d_in[0];
  const float* g_w   = (const float*)d_in[1];
  const float* g_b   = (const float*)d_in[2];
  const float* th_w  = (const float*)d_in[3];
  const float* th_b  = (const float*)d_in[4];
  const float* ph_w  = (const float*)d_in[5];
  const float* ph_b  = (const float*)d_in[6];
  const float* W_w   = (const float*)d_in[7];
  const float* W_b   = (const float*)d_in[8];
  const float* gamma = (const float*)d_in[9];
  const float* beta  = (const float*)d_in[10];
  float* out = (float*)d_out;
  char* ws = (char*)d_ws;

  const size_t MB = 1024 * 1024;
  ushort_t* vbf  = (ushort_t*)(ws);             // 32 MiB (dead after GEMM1; reused as Wy)
  ushort_t* P    = (ushort_t*)(ws + 32 * MB);   // 48 MiB: [gv | th | ph] 16384x1536
  ushort_t* gvT  = (ushort_t*)(ws + 80 * MB);   // 16 MiB: 4 x 512 x 4096
  ushort_t* phT  = (ushort_t*)(ws + 96 * MB);   // 16 MiB
  ushort_t* MT   = (ushort_t*)(ws + 112 * MB);  // 2 MiB: 4 x 512 x 512 (M^T, pre-scaled 1/N)
  ushort_t* y    = (ushort_t*)(ws + 114 * MB);  // 16 MiB: 16384 x 512
  ushort_t* Wcat = (ushort_t*)(ws + 130 * MB);  // 3 MiB
  ushort_t* Wwb  = (ushort_t*)(ws + 133 * MB);  // 1 MiB
  float* biasc   = (float*)(ws + 134 * MB);                  // 6 KiB
  float* stats   = (float*)(ws + 134 * MB + 64 * 1024);      // 8 KiB
  float* scsh    = (float*)(ws + 134 * MB + 128 * 1024);     // 8 KiB
  ushort_t* Wy = vbf;

  (void)hipMemsetAsync(stats, 0, 2048 * sizeof(float), stream);
  pack_weights<<<8192, 256, 0, stream>>>(g_w, th_w, ph_w, W_w, g_b, th_b, ph_b, Wcat, Wwb, biasc);
  cast_f32_bf16<<<16384, 256, 0, stream>>>(v, vbf);

  // GEMM1: P = v_bf (16384x1024) @ Wcat^T -> 16384x1536 (+bias)
  gemm_bt<128, 128, true><<<dim3(128, 12, 1), 256, 0, stream>>>(
      vbf, Wcat, P, biasc, 1024, 1024, 1024, 1536, 0, 0, 0, 1.0f);

  // transposes for phi^T g: gvT[b][j][n] = gv[b][n][j]; phT[b][i][n] = ph[b][n][i]
  transpose_cols<<<dim3(128, 16, 4), dim3(32, 8), 0, stream>>>(P, 0, gvT);
  transpose_cols<<<dim3(128, 16, 4), dim3(32, 8), 0, stream>>>(P, 1024, phT);

  // GEMM2 (batched): MT[b][j][i] = (1/4096) * sum_n gv[n][j] * ph[n][i]
  gemm_bt<64, 64, false><<<dim3(8, 8, 4), 256, 0, stream>>>(
      gvT, phT, MT, nullptr, 4096, 4096, 4096, 512,
      512L * 4096, 512L * 4096, 512L * 512, 1.0f / 4096.0f);

  // GEMM3 (batched): y[b][n][j] = sum_i th[b][n][i] * MT[b][j][i]
  gemm_bt<128, 128, false><<<dim3(32, 4, 4), 256, 0, stream>>>(
      P + 512, MT, y, nullptr, 512, 1536, 512, 512,
      4096L * 1536, 512L * 512, 4096L * 512, 1.0f);

  // GEMM4: Wy = y (16384x512) @ W_w^T + W_b -> 16384x1024
  gemm_bt<128, 128, true><<<dim3(128, 8, 1), 256, 0, stream>>>(
      y, Wwb, Wy, W_b, 512, 512, 512, 1024, 0, 0, 0, 1.0f);

  bn_stats<<<dim3(4, 64), 256, 0, stream>>>(Wy, stats);
  bn_finalize<<<4, 256, 0, stream>>>(stats, gamma, beta, scsh);
  bn_apply<<<8192, 256, 0, stream>>>(Wy, v, scsh, out);
}

// Round 2
// 336.173 us; speedup vs baseline: 1.1068x; 1.1068x over previous
//
#include <hip/hip_runtime.h>
#include <stdint.h>

typedef unsigned short ushort_t;
typedef __attribute__((ext_vector_type(8))) short bf16x8;   // 8 bf16 in 4 VGPRs
typedef __attribute__((ext_vector_type(4))) float f32x4;

__device__ __forceinline__ float bf2f(unsigned short u) {
  return __uint_as_float(((unsigned)u) << 16);
}
__device__ __forceinline__ unsigned short f2bf(float f) {
  unsigned u = __float_as_uint(f);
  u += 0x7FFFu + ((u >> 16) & 1u);   // RNE
  return (unsigned short)(u >> 16);
}

__device__ __forceinline__ void gload_lds16(const ushort_t* g, ushort_t* l) {
  __builtin_amdgcn_global_load_lds(
      (__attribute__((address_space(1))) void*)(void*)g,
      (__attribute__((address_space(3))) void*)(void*)l, 16, 0, 0);
}

// ---------------- pack weights: Wcat (1536x1024 bf16), Ww (1024x512 bf16), bias_cat ----
__global__ void pack_weights(const float* __restrict__ g_w, const float* __restrict__ th_w,
                             const float* __restrict__ ph_w, const float* __restrict__ W_w,
                             const float* __restrict__ g_b, const float* __restrict__ th_b,
                             const float* __restrict__ ph_b,
                             ushort_t* __restrict__ Wcat, ushort_t* __restrict__ Ww,
                             float* __restrict__ bias_cat) {
  int i = blockIdx.x * 256 + threadIdx.x;
  if (i < 1536 * 1024) {
    int r = i >> 10;
    float val;
    if (r < 512)        val = g_w[i];
    else if (r < 1024)  val = th_w[i - 512 * 1024];
    else                val = ph_w[i - 1024 * 1024];
    Wcat[i] = f2bf(val);
  } else if (i < 1536 * 1024 + 512 * 1024) {
    int j = i - 1536 * 1024;
    Ww[j] = f2bf(W_w[j]);   // W_w is (1024, 512) row-major == B^T layout
  }
  if (i < 512)        bias_cat[i] = g_b[i];
  else if (i < 1024)  bias_cat[i] = th_b[i - 512];
  else if (i < 1536)  bias_cat[i] = ph_b[i - 1024];
}

// ---------------- cast v (fp32) -> bf16 --------------------------------------------
__global__ void cast_f32_bf16(const float* __restrict__ in, ushort_t* __restrict__ out) {
  size_t i = ((size_t)blockIdx.x * 256 + threadIdx.x) * 4;
  float4 f = *(const float4*)(in + i);
  ushort_t o0 = f2bf(f.x), o1 = f2bf(f.y), o2 = f2bf(f.z), o3 = f2bf(f.w);
  unsigned lo = (unsigned)o0 | ((unsigned)o1 << 16);
  unsigned hi = (unsigned)o2 | ((unsigned)o3 << 16);
  *(uint2*)(out + i) = make_uint2(lo, hi);
}

// ---------------- LDS tile transpose: out[b][j][n] = P[b*4096+n][coff+j] ------------
__global__ void transpose_cols(const ushort_t* __restrict__ P, int coff,
                               ushort_t* __restrict__ out) {
  __shared__ ushort_t t[32][33];
  int b = blockIdx.z;
  int n0 = blockIdx.x * 32, j0 = blockIdx.y * 32;
  const ushort_t* Pb = P + (size_t)b * 4096 * 1536 + coff;
  for (int r = threadIdx.y; r < 32; r += 8)
    t[r][threadIdx.x] = Pb[(size_t)(n0 + r) * 1536 + j0 + threadIdx.x];
  __syncthreads();
  ushort_t* ob = out + (size_t)b * 512 * 4096;
  for (int r = threadIdx.y; r < 32; r += 8)
    ob[(size_t)(j0 + r) * 4096 + n0 + threadIdx.x] = t[threadIdx.x][r];
}

// ---------------- bf16 GEMM: C[m][n] = alpha * sum_k A[m][k]*BT[n][k] (+ bias[n]) ---
// 256 threads = 4 waves in 2x2 grid; per-wave (BM/2)x(BN/2) via 16x16x32 MFMA frags.
// STATS: per-column sum/sumsq of the fp32 epilogue values -> atomicAdd into stats_out.
template <int BM, int BN, bool BIAS, bool STATS>
__global__ __launch_bounds__(256) void gemm_bt(
    const ushort_t* __restrict__ A, const ushort_t* __restrict__ B,
    ushort_t* __restrict__ C, const float* __restrict__ bias,
    int K, int lda, int ldb, int ldc, long sA, long sB, long sC, float alpha,
    float* __restrict__ stats_out) {
  constexpr int FR_M = BM / 32, FR_N = BN / 32;
  __shared__ ushort_t As[BM * 64];
  __shared__ ushort_t Bs[BN * 64];
  const int tid = threadIdx.x;
  const int lane = tid & 63;
  const int wm = tid >> 7;         // wave row (0..1)
  const int wn = (tid >> 6) & 1;   // wave col (0..1)
  const long b = blockIdx.z;
  A += b * sA; B += b * sB; C += b * sC;
  const int tm0 = blockIdx.x * BM, tn0 = blockIdx.y * BN;

  f32x4 acc[FR_M][FR_N] = {};

  for (int kt = 0; kt < K; kt += 64) {
#pragma unroll
    for (int it = 0; it < BM / 32; ++it) {
      int g = it * 256 + tid;
      gload_lds16(A + (long)(tm0 + (g >> 3)) * lda + kt + (g & 7) * 8, &As[g * 8]);
    }
#pragma unroll
    for (int it = 0; it < BN / 32; ++it) {
      int g = it * 256 + tid;
      gload_lds16(B + (long)(tn0 + (g >> 3)) * ldb + kt + (g & 7) * 8, &Bs[g * 8]);
    }
    __syncthreads();   // drains vmcnt before barrier
#pragma unroll
    for (int kk = 0; kk < 2; ++kk) {
      bf16x8 af[FR_M], bfr[FR_N];
#pragma unroll
      for (int m = 0; m < FR_M; ++m)
        af[m] = *(const bf16x8*)&As[(wm * (BM / 2) + m * 16 + (lane & 15)) * 64 +
                                    kk * 32 + (lane >> 4) * 8];
#pragma unroll
      for (int n = 0; n < FR_N; ++n)
        bfr[n] = *(const bf16x8*)&Bs[(wn * (BN / 2) + n * 16 + (lane & 15)) * 64 +
                                     kk * 32 + (lane >> 4) * 8];
#pragma unroll
      for (int m = 0; m < FR_M; ++m)
#pragma unroll
        for (int n = 0; n < FR_N; ++n)
          acc[m][n] = __builtin_amdgcn_mfma_f32_16x16x32_bf16(af[m], bfr[n], acc[m][n], 0, 0, 0);
    }
    __syncthreads();
  }

#pragma unroll
  for (int n = 0; n < FR_N; ++n) {
    const int col = tn0 + wn * (BN / 2) + n * 16 + (lane & 15);
    const float bv = BIAS ? bias[col] : 0.0f;
    float s = 0.f, s2 = 0.f;
#pragma unroll
    for (int m = 0; m < FR_M; ++m) {
#pragma unroll
      for (int r = 0; r < 4; ++r) {
        const int row = tm0 + wm * (BM / 2) + m * 16 + (lane >> 4) * 4 + r;
        float val = alpha * acc[m][n][r] + bv;
        C[(long)row * ldc + col] = f2bf(val);
        if (STATS) { s += val; s2 += val * val; }
      }
    }
    if (STATS) {
      s  += __shfl_xor(s, 16);  s  += __shfl_xor(s, 32);
      s2 += __shfl_xor(s2, 16); s2 += __shfl_xor(s2, 32);
      if ((lane >> 4) == 0) {
        atomicAdd(&stats_out[col], s);
        atomicAdd(&stats_out[1024 + col], s2);
      }
    }
  }
}

// ---------------- split-K GEMM2: Mpart[b*4+kc][i][j] = (1/4096) * partial ----------
// A=phT [b][i][n] (512x4096), B=gvT [b][j][n]; K chunk = 1024 per kc.
__global__ __launch_bounds__(256) void gemm_splitk64(
    const ushort_t* __restrict__ A, const ushort_t* __restrict__ B,
    float* __restrict__ Cp) {
  __shared__ ushort_t As[64 * 64];
  __shared__ ushort_t Bs[64 * 64];
  const int tid = threadIdx.x;
  const int lane = tid & 63;
  const int wm = tid >> 7;
  const int wn = (tid >> 6) & 1;
  const int b = blockIdx.z >> 2, kc = blockIdx.z & 3;
  const ushort_t* Ab = A + (size_t)b * 512 * 4096 + kc * 1024;
  const ushort_t* Bb = B + (size_t)b * 512 * 4096 + kc * 1024;
  float* Cb = Cp + (size_t)blockIdx.z * 512 * 512;
  const int tm0 = blockIdx.x * 64, tn0 = blockIdx.y * 64;

  f32x4 acc[2][2] = {};

  for (int kt = 0; kt < 1024; kt += 64) {
#pragma unroll
    for (int it = 0; it < 2; ++it) {
      int g = it * 256 + tid;
      gload_lds16(Ab + (long)(tm0 + (g >> 3)) * 4096 + kt + (g & 7) * 8, &As[g * 8]);
    }
#pragma unroll
    for (int it = 0; it < 2; ++it) {
      int g = it * 256 + tid;
      gload_lds16(Bb + (long)(tn0 + (g >> 3)) * 4096 + kt + (g & 7) * 8, &Bs[g * 8]);
    }
    __syncthreads();
#pragma unroll
    for (int kk = 0; kk < 2; ++kk) {
      bf16x8 af[2], bfr[2];
#pragma unroll
      for (int m = 0; m < 2; ++m)
        af[m] = *(const bf16x8*)&As[(wm * 32 + m * 16 + (lane & 15)) * 64 +
                                    kk * 32 + (lane >> 4) * 8];
#pragma unroll
      for (int n = 0; n < 2; ++n)
        bfr[n] = *(const bf16x8*)&Bs[(wn * 32 + n * 16 + (lane & 15)) * 64 +
                                     kk * 32 + (lane >> 4) * 8];
#pragma unroll
      for (int m = 0; m < 2; ++m)
#pragma unroll
        for (int n = 0; n < 2; ++n)
          acc[m][n] = __builtin_amdgcn_mfma_f32_16x16x32_bf16(af[m], bfr[n], acc[m][n], 0, 0, 0);
    }
    __syncthreads();
  }

#pragma unroll
  for (int m = 0; m < 2; ++m)
#pragma unroll
    for (int n = 0; n < 2; ++n) {
      const int col = tn0 + wn * 32 + n * 16 + (lane & 15);
#pragma unroll
      for (int r = 0; r < 4; ++r) {
        const int row = tm0 + wm * 32 + m * 16 + (lane >> 4) * 4 + r;
        Cb[(long)row * 512 + col] = (1.0f / 4096.0f) * acc[m][n][r];
      }
    }
}

// ---------------- reduce 4 K-partials -> Mb bf16 [b][i][j] --------------------------
__global__ void reduce_cast_m(const float* __restrict__ Mpart, ushort_t* __restrict__ Mb) {
  int i = blockIdx.x * 256 + threadIdx.x;    // 262144 float4-groups (4 batches)
  int b = i >> 16;                           // 65536 groups per batch
  int off = i & 65535;
  const float4* base = (const float4*)Mpart;
  float4 s  = base[(size_t)(b * 4 + 0) * 65536 + off];
  float4 t1 = base[(size_t)(b * 4 + 1) * 65536 + off];
  float4 t2 = base[(size_t)(b * 4 + 2) * 65536 + off];
  float4 t3 = base[(size_t)(b * 4 + 3) * 65536 + off];
  s.x += t1.x + t2.x + t3.x;
  s.y += t1.y + t2.y + t3.y;
  s.z += t1.z + t2.z + t3.z;
  s.w += t1.w + t2.w + t3.w;
  unsigned lo = (unsigned)f2bf(s.x) | (((unsigned)f2bf(s.y)) << 16);
  unsigned hi = (unsigned)f2bf(s.z) | (((unsigned)f2bf(s.w)) << 16);
  *(uint2*)(Mb + (size_t)i * 4) = make_uint2(lo, hi);
}

__global__ void bn_finalize(const float* __restrict__ sums, const float* __restrict__ gamma,
                            const float* __restrict__ beta, float* __restrict__ scsh) {
  int c = blockIdx.x * 256 + threadIdx.x;
  float mean = sums[c] * (1.0f / 16384.0f);
  float var = sums[1024 + c] * (1.0f / 16384.0f) - mean * mean;
  float sc = gamma[c] * rsqrtf(var + 1e-5f);
  scsh[c] = sc;
  scsh[1024 + c] = beta[c] - mean * sc;
}

// ---------------- apply BN + residual: out = Wy*scale + shift + v -------------------
__global__ void bn_apply(const ushort_t* __restrict__ Wy, const float* __restrict__ v,
                         const float* __restrict__ scsh, float* __restrict__ out) {
  size_t i = ((size_t)blockIdx.x * 256 + threadIdx.x) * 8;
  int c0 = (int)(i & 1023);
  bf16x8 w = *(const bf16x8*)(Wy + i);
  float4 v0 = *(const float4*)(v + i);
  float4 v1 = *(const float4*)(v + i + 4);
  float4 sc0 = *(const float4*)(scsh + c0);
  float4 sc1 = *(const float4*)(scsh + c0 + 4);
  float4 sh0 = *(const float4*)(scsh + 1024 + c0);
  float4 sh1 = *(const float4*)(scsh + 1024 + c0 + 4);
  float4 o0, o1;
  o0.x = bf2f((unsigned short)w[0]) * sc0.x + sh0.x + v0.x;
  o0.y = bf2f((unsigned short)w[1]) * sc0.y + sh0.y + v0.y;
  o0.z = bf2f((unsigned short)w[2]) * sc0.z + sh0.z + v0.z;
  o0.w = bf2f((unsigned short)w[3]) * sc0.w + sh0.w + v0.w;
  o1.x = bf2f((unsigned short)w[4]) * sc1.x + sh1.x + v1.x;
  o1.y = bf2f((unsigned short)w[5]) * sc1.y + sh1.y + v1.y;
  o1.z = bf2f((unsigned short)w[6]) * sc1.z + sh1.z + v1.z;
  o1.w = bf2f((unsigned short)w[7]) * sc1.w + sh1.w + v1.w;
  *(float4*)(out + i) = o0;
  *(float4*)(out + i + 4) = o1;
}

extern "C" void kernel_launch(void* const* d_in, const int* in_sizes, int n_in,
                              void* d_out, int out_size, void* d_ws, size_t ws_size,
                              hipStream_t stream) {
  const float* v     = (const float*)d_in[0];
  const float* g_w   = (const float*)d_in[1];
  const float* g_b   = (const float*)d_in[2];
  const float* th_w  = (const float*)d_in[3];
  const float* th_b  = (const float*)d_in[4];
  const float* ph_w  = (const float*)d_in[5];
  const float* ph_b  = (const float*)d_in[6];
  const float* W_w   = (const float*)d_in[7];
  const float* W_b   = (const float*)d_in[8];
  const float* gamma = (const float*)d_in[9];
  const float* beta  = (const float*)d_in[10];
  float* out = (float*)d_out;
  char* ws = (char*)d_ws;

  const size_t MB = 1024 * 1024;
  // Region plan (max 134MB+144KB, identical envelope to round 1):
  //  [0,32)    vbf (dead after GEMM1) -> Qb @0 (4MB) after
  //  [32,80)   P = [gv|th|ph] 16384x1536
  //  [80,112)  gvT (16MB) + phT (16MB); both dead after splitk -> Wy @80 (32MB)
  //  [112,128) Mpart (16 x 512x512 fp32)
  //  [128,130) Mb bf16
  //  [130,133) Wcat, [133,134) Wwb, [134..] biasc/stats/scsh
  ushort_t* vbf   = (ushort_t*)(ws);
  ushort_t* P     = (ushort_t*)(ws + 32 * MB);
  ushort_t* gvT   = (ushort_t*)(ws + 80 * MB);
  ushort_t* phT   = (ushort_t*)(ws + 96 * MB);
  ushort_t* Wy    = (ushort_t*)(ws + 80 * MB);
  float*    Mpart = (float*)(ws + 112 * MB);
  ushort_t* Mb    = (ushort_t*)(ws + 128 * MB);
  ushort_t* Qb    = (ushort_t*)(ws);
  ushort_t* Wcat  = (ushort_t*)(ws + 130 * MB);
  ushort_t* Wwb   = (ushort_t*)(ws + 133 * MB);
  float* biasc    = (float*)(ws + 134 * MB);
  float* stats    = (float*)(ws + 134 * MB + 64 * 1024);
  float* scsh     = (float*)(ws + 134 * MB + 128 * 1024);

  (void)hipMemsetAsync(stats, 0, 2048 * sizeof(float), stream);
  pack_weights<<<8192, 256, 0, stream>>>(g_w, th_w, ph_w, W_w, g_b, th_b, ph_b, Wcat, Wwb, biasc);
  cast_f32_bf16<<<16384, 256, 0, stream>>>(v, vbf);

  // GEMM1: P = v_bf (16384x1024) @ Wcat^T -> 16384x1536 (+bias)
  gemm_bt<128, 128, true, false><<<dim3(128, 12, 1), 256, 0, stream>>>(
      vbf, Wcat, P, biasc, 1024, 1024, 1024, 1536, 0, 0, 0, 1.0f, nullptr);

  // transposes: gvT[b][j][n] = gv[b][n][j]; phT[b][i][n] = ph[b][n][i]
  transpose_cols<<<dim3(128, 16, 4), dim3(32, 8), 0, stream>>>(P, 0, gvT);
  transpose_cols<<<dim3(128, 16, 4), dim3(32, 8), 0, stream>>>(P, 1024, phT);

  // GEMM2 split-K: M[b][i][j] = (1/4096) sum_n ph[n][i] gv[n][j]  (fp32 partials)
  gemm_splitk64<<<dim3(8, 8, 16), 256, 0, stream>>>(phT, gvT, Mpart);
  reduce_cast_m<<<1024, 256, 0, stream>>>(Mpart, Mb);

  // Q-GEMM: Q[b][c][i] = sum_j W_w[c][j] * M[b][i][j]   (1024x512 per batch)
  gemm_bt<64, 64, false, false><<<dim3(16, 8, 4), 256, 0, stream>>>(
      Wwb, Mb, Qb, nullptr, 512, 512, 512, 512,
      0, 512L * 512, 1024L * 512, 1.0f, nullptr);

  // GEMM3': Wy[b][n][c] = sum_i th[b][n][i] * Q[b][c][i] + W_b[c]  (+fused BN stats)
  gemm_bt<128, 128, true, true><<<dim3(32, 8, 4), 256, 0, stream>>>(
      P + 512, Qb, Wy, W_b, 512, 1536, 512, 1024,
      4096L * 1536, 1024L * 512, 4096L * 1024, 1.0f, stats);

  bn_finalize<<<4, 256, 0, stream>>>(stats, gamma, beta, scsh);
  bn_apply<<<8192, 256, 0, stream>>>(Wy, v, scsh, out);
}

// Round 3
// 312.842 us; speedup vs baseline: 1.1894x; 1.0746x over previous
//
#include <hip/hip_runtime.h>
#include <stdint.h>

typedef unsigned short ushort_t;
typedef __attribute__((ext_vector_type(8))) short bf16x8;   // 8 bf16 in 4 VGPRs
typedef __attribute__((ext_vector_type(4))) float f32x4;

__device__ __forceinline__ float bf2f(unsigned short u) {
  return __uint_as_float(((unsigned)u) << 16);
}
__device__ __forceinline__ unsigned short f2bf(float f) {
  unsigned u = __float_as_uint(f);
  u += 0x7FFFu + ((u >> 16) & 1u);   // RNE
  return (unsigned short)(u >> 16);
}

__device__ __forceinline__ void gload_lds16(const ushort_t* g, ushort_t* l) {
  __builtin_amdgcn_global_load_lds(
      (__attribute__((address_space(1))) void*)(void*)g,
      (__attribute__((address_space(3))) void*)(void*)l, 16, 0, 0);
}

// ---------------- pack weights: Wcat (1536x1024 bf16), Ww (1024x512 bf16), bias_cat ----
__global__ void pack_weights(const float* __restrict__ g_w, const float* __restrict__ th_w,
                             const float* __restrict__ ph_w, const float* __restrict__ W_w,
                             const float* __restrict__ g_b, const float* __restrict__ th_b,
                             const float* __restrict__ ph_b,
                             ushort_t* __restrict__ Wcat, ushort_t* __restrict__ Ww,
                             float* __restrict__ bias_cat) {
  int i = blockIdx.x * 256 + threadIdx.x;
  if (i < 1536 * 1024) {
    int r = i >> 10;
    float val;
    if (r < 512)        val = g_w[i];
    else if (r < 1024)  val = th_w[i - 512 * 1024];
    else                val = ph_w[i - 1024 * 1024];
    Wcat[i] = f2bf(val);
  } else if (i < 1536 * 1024 + 512 * 1024) {
    int j = i - 1536 * 1024;
    Ww[j] = f2bf(W_w[j]);   // W_w is (1024, 512) row-major == B^T layout
  }
  if (i < 512)        bias_cat[i] = g_b[i];
  else if (i < 1024)  bias_cat[i] = th_b[i - 512];
  else if (i < 1536)  bias_cat[i] = ph_b[i - 1024];
}

// ---------------- cast v (fp32) -> bf16 --------------------------------------------
__global__ void cast_f32_bf16(const float* __restrict__ in, ushort_t* __restrict__ out) {
  size_t i = ((size_t)blockIdx.x * 256 + threadIdx.x) * 4;
  float4 f = *(const float4*)(in + i);
  ushort_t o0 = f2bf(f.x), o1 = f2bf(f.y), o2 = f2bf(f.z), o3 = f2bf(f.w);
  unsigned lo = (unsigned)o0 | ((unsigned)o1 << 16);
  unsigned hi = (unsigned)o2 | ((unsigned)o3 << 16);
  *(uint2*)(out + i) = make_uint2(lo, hi);
}

// ---------------- GEMM1: P-projections with layout-split epilogue -------------------
// A = vbf (16384x1024), B = Wcat^T (1536x1024). Output column ranges:
//   [0,512)     -> gvT[b][c][n]       (transposed, b = n>>12)
//   [512,1024)  -> th[n][c-512]       (row-major, ld=512)
//   [1024,1536) -> phT[b][c-1024][n]  (transposed)
__global__ __launch_bounds__(256) void gemm1(
    const ushort_t* __restrict__ A, const ushort_t* __restrict__ B,
    ushort_t* __restrict__ gvT, ushort_t* __restrict__ th, ushort_t* __restrict__ phT,
    const float* __restrict__ bias) {
  constexpr int BM = 128, BN = 128, FR_M = 4, FR_N = 4;
  __shared__ ushort_t As[BM * 64];
  __shared__ ushort_t Bs[BN * 64];
  const int tid = threadIdx.x;
  const int lane = tid & 63;
  const int wm = tid >> 7;
  const int wn = (tid >> 6) & 1;
  const int tm0 = blockIdx.x * BM, tn0 = blockIdx.y * BN;

  f32x4 acc[FR_M][FR_N] = {};

  for (int kt = 0; kt < 1024; kt += 64) {
#pragma unroll
    for (int it = 0; it < 4; ++it) {
      int g = it * 256 + tid;
      gload_lds16(A + (long)(tm0 + (g >> 3)) * 1024 + kt + (g & 7) * 8, &As[g * 8]);
    }
#pragma unroll
    for (int it = 0; it < 4; ++it) {
      int g = it * 256 + tid;
      gload_lds16(B + (long)(tn0 + (g >> 3)) * 1024 + kt + (g & 7) * 8, &Bs[g * 8]);
    }
    __syncthreads();
#pragma unroll
    for (int kk = 0; kk < 2; ++kk) {
      bf16x8 af[FR_M], bfr[FR_N];
#pragma unroll
      for (int m = 0; m < FR_M; ++m)
        af[m] = *(const bf16x8*)&As[(wm * 64 + m * 16 + (lane & 15)) * 64 +
                                    kk * 32 + (lane >> 4) * 8];
#pragma unroll
      for (int n = 0; n < FR_N; ++n)
        bfr[n] = *(const bf16x8*)&Bs[(wn * 64 + n * 16 + (lane & 15)) * 64 +
                                     kk * 32 + (lane >> 4) * 8];
#pragma unroll
      for (int m = 0; m < FR_M; ++m)
#pragma unroll
        for (int n = 0; n < FR_N; ++n)
          acc[m][n] = __builtin_amdgcn_mfma_f32_16x16x32_bf16(af[m], bfr[n], acc[m][n], 0, 0, 0);
    }
    __syncthreads();
  }

  // epilogue: region is uniform per block (tn0 multiple of 128)
  if (tn0 != 512 + (tn0 & 383)) { }  // no-op; keep structure simple below
  if (tn0 < 512 || tn0 >= 1024) {
    ushort_t* T = (tn0 < 512) ? gvT : phT;
    const int coff = (tn0 < 512) ? 0 : 1024;
#pragma unroll
    for (int m = 0; m < FR_M; ++m) {
      const int row0 = tm0 + wm * 64 + m * 16 + (lane >> 4) * 4;
      const int b = row0 >> 12, np = row0 & 4095;
#pragma unroll
      for (int n = 0; n < FR_N; ++n) {
        const int col = tn0 - coff + wn * 64 + n * 16 + (lane & 15);
        const float bv = bias[tn0 + wn * 64 + n * 16 + (lane & 15)];
        unsigned lo = (unsigned)f2bf(acc[m][n][0] + bv) | (((unsigned)f2bf(acc[m][n][1] + bv)) << 16);
        unsigned hi = (unsigned)f2bf(acc[m][n][2] + bv) | (((unsigned)f2bf(acc[m][n][3] + bv)) << 16);
        *(uint2*)(T + ((size_t)(b * 512 + col)) * 4096 + np) = make_uint2(lo, hi);
      }
    }
  } else {
#pragma unroll
    for (int n = 0; n < FR_N; ++n) {
      const int gcol = tn0 + wn * 64 + n * 16 + (lane & 15);
      const float bv = bias[gcol];
      const int col = gcol - 512;
#pragma unroll
      for (int m = 0; m < FR_M; ++m) {
#pragma unroll
        for (int r = 0; r < 4; ++r) {
          const int row = tm0 + wm * 64 + m * 16 + (lane >> 4) * 4 + r;
          th[(size_t)row * 512 + col] = f2bf(acc[m][n][r] + bv);
        }
      }
    }
  }
}

// ---------------- bf16 GEMM: C[m][n] = alpha * sum_k A[m][k]*BT[n][k] (+ bias[n]) ---
template <int BM, int BN, bool BIAS, bool STATS>
__global__ __launch_bounds__(256) void gemm_bt(
    const ushort_t* __restrict__ A, const ushort_t* __restrict__ B,
    ushort_t* __restrict__ C, const float* __restrict__ bias,
    int K, int lda, int ldb, int ldc, long sA, long sB, long sC, float alpha,
    float* __restrict__ stats_out) {
  constexpr int FR_M = BM / 32, FR_N = BN / 32;
  __shared__ ushort_t As[BM * 64];
  __shared__ ushort_t Bs[BN * 64];
  const int tid = threadIdx.x;
  const int lane = tid & 63;
  const int wm = tid >> 7;
  const int wn = (tid >> 6) & 1;
  const long b = blockIdx.z;
  A += b * sA; B += b * sB; C += b * sC;
  const int tm0 = blockIdx.x * BM, tn0 = blockIdx.y * BN;

  f32x4 acc[FR_M][FR_N] = {};

  for (int kt = 0; kt < K; kt += 64) {
#pragma unroll
    for (int it = 0; it < BM / 32; ++it) {
      int g = it * 256 + tid;
      gload_lds16(A + (long)(tm0 + (g >> 3)) * lda + kt + (g & 7) * 8, &As[g * 8]);
    }
#pragma unroll
    for (int it = 0; it < BN / 32; ++it) {
      int g = it * 256 + tid;
      gload_lds16(B + (long)(tn0 + (g >> 3)) * ldb + kt + (g & 7) * 8, &Bs[g * 8]);
    }
    __syncthreads();
#pragma unroll
    for (int kk = 0; kk < 2; ++kk) {
      bf16x8 af[FR_M], bfr[FR_N];
#pragma unroll
      for (int m = 0; m < FR_M; ++m)
        af[m] = *(const bf16x8*)&As[(wm * (BM / 2) + m * 16 + (lane & 15)) * 64 +
                                    kk * 32 + (lane >> 4) * 8];
#pragma unroll
      for (int n = 0; n < FR_N; ++n)
        bfr[n] = *(const bf16x8*)&Bs[(wn * (BN / 2) + n * 16 + (lane & 15)) * 64 +
                                     kk * 32 + (lane >> 4) * 8];
#pragma unroll
      for (int m = 0; m < FR_M; ++m)
#pragma unroll
        for (int n = 0; n < FR_N; ++n)
          acc[m][n] = __builtin_amdgcn_mfma_f32_16x16x32_bf16(af[m], bfr[n], acc[m][n], 0, 0, 0);
    }
    __syncthreads();
  }

#pragma unroll
  for (int n = 0; n < FR_N; ++n) {
    const int col = tn0 + wn * (BN / 2) + n * 16 + (lane & 15);
    const float bv = BIAS ? bias[col] : 0.0f;
    float s = 0.f, s2 = 0.f;
#pragma unroll
    for (int m = 0; m < FR_M; ++m) {
#pragma unroll
      for (int r = 0; r < 4; ++r) {
        const int row = tm0 + wm * (BM / 2) + m * 16 + (lane >> 4) * 4 + r;
        float val = alpha * acc[m][n][r] + bv;
        C[(long)row * ldc + col] = f2bf(val);
        if (STATS) { s += val; s2 += val * val; }
      }
    }
    if (STATS) {
      s  += __shfl_xor(s, 16);  s  += __shfl_xor(s, 32);
      s2 += __shfl_xor(s2, 16); s2 += __shfl_xor(s2, 32);
      if ((lane >> 4) == 0) {
        atomicAdd(&stats_out[col], s);
        atomicAdd(&stats_out[1024 + col], s2);
      }
    }
  }
}

// ---------------- split-K GEMM2: Mpart[b*4+kc][i][j] (fp32, pre-scaled 1/4096) ------
// A=phT [b][i][n], B=gvT [b][j][n]; K chunk = 1024 per kc.  BM=128, BN=64.
__global__ __launch_bounds__(256) void gemm_splitk(
    const ushort_t* __restrict__ A, const ushort_t* __restrict__ B,
    float* __restrict__ Cp) {
  constexpr int BM = 128, BN = 64, FR_M = 4, FR_N = 2;
  __shared__ ushort_t As[BM * 64];
  __shared__ ushort_t Bs[BN * 64];
  const int tid = threadIdx.x;
  const int lane = tid & 63;
  const int wm = tid >> 7;
  const int wn = (tid >> 6) & 1;
  const int b = blockIdx.z >> 2, kc = blockIdx.z & 3;
  const ushort_t* Ab = A + (size_t)b * 512 * 4096 + kc * 1024;
  const ushort_t* Bb = B + (size_t)b * 512 * 4096 + kc * 1024;
  float* Cb = Cp + (size_t)blockIdx.z * 512 * 512;
  const int tm0 = blockIdx.x * BM, tn0 = blockIdx.y * BN;

  f32x4 acc[FR_M][FR_N] = {};

  for (int kt = 0; kt < 1024; kt += 64) {
#pragma unroll
    for (int it = 0; it < BM / 32; ++it) {
      int g = it * 256 + tid;
      gload_lds16(Ab + (long)(tm0 + (g >> 3)) * 4096 + kt + (g & 7) * 8, &As[g * 8]);
    }
#pragma unroll
    for (int it = 0; it < BN / 32; ++it) {
      int g = it * 256 + tid;
      gload_lds16(Bb + (long)(tn0 + (g >> 3)) * 4096 + kt + (g & 7) * 8, &Bs[g * 8]);
    }
    __syncthreads();
#pragma unroll
    for (int kk = 0; kk < 2; ++kk) {
      bf16x8 af[FR_M], bfr[FR_N];
#pragma unroll
      for (int m = 0; m < FR_M; ++m)
        af[m] = *(const bf16x8*)&As[(wm * (BM / 2) + m * 16 + (lane & 15)) * 64 +
                                    kk * 32 + (lane >> 4) * 8];
#pragma unroll
      for (int n = 0; n < FR_N; ++n)
        bfr[n] = *(const bf16x8*)&Bs[(wn * (BN / 2) + n * 16 + (lane & 15)) * 64 +
                                     kk * 32 + (lane >> 4) * 8];
#pragma unroll
      for (int m = 0; m < FR_M; ++m)
#pragma unroll
        for (int n = 0; n < FR_N; ++n)
          acc[m][n] = __builtin_amdgcn_mfma_f32_16x16x32_bf16(af[m], bfr[n], acc[m][n], 0, 0, 0);
    }
    __syncthreads();
  }

#pragma unroll
  for (int m = 0; m < FR_M; ++m)
#pragma unroll
    for (int n = 0; n < FR_N; ++n) {
      const int col = tn0 + wn * (BN / 2) + n * 16 + (lane & 15);
#pragma unroll
      for (int r = 0; r < 4; ++r) {
        const int row = tm0 + wm * (BM / 2) + m * 16 + (lane >> 4) * 4 + r;
        Cb[(long)row * 512 + col] = (1.0f / 4096.0f) * acc[m][n][r];
      }
    }
}

// ---------------- reduce 4 K-partials -> Mb bf16 [b][i][j] --------------------------
__global__ void reduce_cast_m(const float* __restrict__ Mpart, ushort_t* __restrict__ Mb) {
  int i = blockIdx.x * 256 + threadIdx.x;
  int b = i >> 16;
  int off = i & 65535;
  const float4* base = (const float4*)Mpart;
  float4 s  = base[(size_t)(b * 4 + 0) * 65536 + off];
  float4 t1 = base[(size_t)(b * 4 + 1) * 65536 + off];
  float4 t2 = base[(size_t)(b * 4 + 2) * 65536 + off];
  float4 t3 = base[(size_t)(b * 4 + 3) * 65536 + off];
  s.x += t1.x + t2.x + t3.x;
  s.y += t1.y + t2.y + t3.y;
  s.z += t1.z + t2.z + t3.z;
  s.w += t1.w + t2.w + t3.w;
  unsigned lo = (unsigned)f2bf(s.x) | (((unsigned)f2bf(s.y)) << 16);
  unsigned hi = (unsigned)f2bf(s.z) | (((unsigned)f2bf(s.w)) << 16);
  *(uint2*)(Mb + (size_t)i * 4) = make_uint2(lo, hi);
}

__global__ void bn_finalize(const float* __restrict__ sums, const float* __restrict__ gamma,
                            const float* __restrict__ beta, float* __restrict__ scsh) {
  int c = blockIdx.x * 256 + threadIdx.x;
  float mean = sums[c] * (1.0f / 16384.0f);
  float var = sums[1024 + c] * (1.0f / 16384.0f) - mean * mean;
  float sc = gamma[c] * rsqrtf(var + 1e-5f);
  scsh[c] = sc;
  scsh[1024 + c] = beta[c] - mean * sc;
}

// ---------------- apply BN + residual: out = Wy*scale + shift + v (bf16 v) ----------
__global__ void bn_apply(const ushort_t* __restrict__ Wy, const ushort_t* __restrict__ vbf,
                         const float* __restrict__ scsh, float* __restrict__ out) {
  size_t i = ((size_t)blockIdx.x * 256 + threadIdx.x) * 8;
  int c0 = (int)(i & 1023);
  bf16x8 w = *(const bf16x8*)(Wy + i);
  bf16x8 vv = *(const bf16x8*)(vbf + i);
  float4 sc0 = *(const float4*)(scsh + c0);
  float4 sc1 = *(const float4*)(scsh + c0 + 4);
  float4 sh0 = *(const float4*)(scsh + 1024 + c0);
  float4 sh1 = *(const float4*)(scsh + 1024 + c0 + 4);
  float4 o0, o1;
  o0.x = bf2f((unsigned short)w[0]) * sc0.x + sh0.x + bf2f((unsigned short)vv[0]);
  o0.y = bf2f((unsigned short)w[1]) * sc0.y + sh0.y + bf2f((unsigned short)vv[1]);
  o0.z = bf2f((unsigned short)w[2]) * sc0.z + sh0.z + bf2f((unsigned short)vv[2]);
  o0.w = bf2f((unsigned short)w[3]) * sc0.w + sh0.w + bf2f((unsigned short)vv[3]);
  o1.x = bf2f((unsigned short)w[4]) * sc1.x + sh1.x + bf2f((unsigned short)vv[4]);
  o1.y = bf2f((unsigned short)w[5]) * sc1.y + sh1.y + bf2f((unsigned short)vv[5]);
  o1.z = bf2f((unsigned short)w[6]) * sc1.z + sh1.z + bf2f((unsigned short)vv[6]);
  o1.w = bf2f((unsigned short)w[7]) * sc1.w + sh1.w + bf2f((unsigned short)vv[7]);
  *(float4*)(out + i) = o0;
  *(float4*)(out + i + 4) = o1;
}

extern "C" void kernel_launch(void* const* d_in, const int* in_sizes, int n_in,
                              void* d_out, int out_size, void* d_ws, size_t ws_size,
                              hipStream_t stream) {
  const float* v     = (const float*)d_in[0];
  const float* g_w   = (const float*)d_in[1];
  const float* g_b   = (const float*)d_in[2];
  const float* th_w  = (const float*)d_in[3];
  const float* th_b  = (const float*)d_in[4];
  const float* ph_w  = (const float*)d_in[5];
  const float* ph_b  = (const float*)d_in[6];
  const float* W_w   = (const float*)d_in[7];
  const float* W_b   = (const float*)d_in[8];
  const float* gamma = (const float*)d_in[9];
  const float* beta  = (const float*)d_in[10];
  float* out = (float*)d_out;
  char* ws = (char*)d_ws;

  const size_t MB = 1024 * 1024;
  // Lifetime-packed plan (max 107 MB):
  //  [0,32)   vbf          cast -> gemm1, bn_apply
  //  [32,48)  th           gemm1 -> gemm3'
  //  [48,64)  gvT          gemm1 -> splitk   }  overlaid by Wy after splitk
  //  [64,80)  phT          gemm1 -> splitk   }
  //  [80,96)  Mpart        splitk -> reduce
  //  [96,98)  Mb, [98,102) Qb, [102,105) Wcat, [105,106) Wwb, [106,...) misc
  ushort_t* vbf   = (ushort_t*)(ws);
  ushort_t* th    = (ushort_t*)(ws + 32 * MB);
  ushort_t* gvT   = (ushort_t*)(ws + 48 * MB);
  ushort_t* phT   = (ushort_t*)(ws + 64 * MB);
  ushort_t* Wy    = (ushort_t*)(ws + 48 * MB);
  float*    Mpart = (float*)(ws + 80 * MB);
  ushort_t* Mb    = (ushort_t*)(ws + 96 * MB);
  ushort_t* Qb    = (ushort_t*)(ws + 98 * MB);
  ushort_t* Wcat  = (ushort_t*)(ws + 102 * MB);
  ushort_t* Wwb   = (ushort_t*)(ws + 105 * MB);
  float* biasc    = (float*)(ws + 106 * MB);
  float* stats    = (float*)(ws + 106 * MB + 64 * 1024);
  float* scsh     = (float*)(ws + 106 * MB + 128 * 1024);

  (void)hipMemsetAsync(stats, 0, 2048 * sizeof(float), stream);
  pack_weights<<<8192, 256, 0, stream>>>(g_w, th_w, ph_w, W_w, g_b, th_b, ph_b, Wcat, Wwb, biasc);
  cast_f32_bf16<<<16384, 256, 0, stream>>>(v, vbf);

  // GEMM1: projections; gv/ph written transposed, th row-major (ld=512)
  gemm1<<<dim3(128, 12), 256, 0, stream>>>(vbf, Wcat, gvT, th, phT, biasc);

  // GEMM2 split-K: M~[i][j] = (1/4096) sum_n ph[n][i] gv[n][j]  (fp32 partials)
  gemm_splitk<<<dim3(4, 8, 16), 256, 0, stream>>>(phT, gvT, Mpart);
  reduce_cast_m<<<1024, 256, 0, stream>>>(Mpart, Mb);

  // Q-GEMM: Q[c][i] = sum_k Ww[c][k] * M~[i][k]
  gemm_bt<64, 64, false, false><<<dim3(16, 8, 4), 256, 0, stream>>>(
      Wwb, Mb, Qb, nullptr, 512, 512, 512, 512,
      0, 512L * 512, 1024L * 512, 1.0f, nullptr);

  // GEMM3': Wy[n][c] = sum_j th[n][j] * Q[c][j] + W_b[c]  (+fused BN stats)
  gemm_bt<128, 128, true, true><<<dim3(32, 8, 4), 256, 0, stream>>>(
      th, Qb, Wy, W_b, 512, 512, 512, 1024,
      4096L * 512, 1024L * 512, 4096L * 1024, 1.0f, stats);

  bn_finalize<<<4, 256, 0, stream>>>(stats, gamma, beta, scsh);
  bn_apply<<<8192, 256, 0, stream>>>(Wy, vbf, scsh, out);
}

// Round 4
// 309.110 us; speedup vs baseline: 1.2037x; 1.0121x over previous
//
#include <hip/hip_runtime.h>
#include <stdint.h>

typedef unsigned short ushort_t;
typedef __attribute__((ext_vector_type(8))) short bf16x8;   // 8 bf16 in 4 VGPRs
typedef __attribute__((ext_vector_type(4))) float f32x4;

__device__ __forceinline__ float bf2f(unsigned short u) {
  return __uint_as_float(((unsigned)u) << 16);
}
__device__ __forceinline__ unsigned short f2bf(float f) {
  unsigned u = __float_as_uint(f);
  u += 0x7FFFu + ((u >> 16) & 1u);   // RNE
  return (unsigned short)(u >> 16);
}

__device__ __forceinline__ void gload_lds16(const ushort_t* g, ushort_t* l) {
  __builtin_amdgcn_global_load_lds(
      (__attribute__((address_space(1))) void*)(void*)g,
      (__attribute__((address_space(3))) void*)(void*)l, 16, 0, 0);
}

// ------------- merged: cast v->bf16 (blocks [0,16384)) + pack weights (rest) --------
__global__ void prep(const float* __restrict__ v,
                     const float* __restrict__ g_w, const float* __restrict__ th_w,
                     const float* __restrict__ ph_w, const float* __restrict__ W_w,
                     const float* __restrict__ g_b, const float* __restrict__ th_b,
                     const float* __restrict__ ph_b,
                     ushort_t* __restrict__ vbf,
                     ushort_t* __restrict__ Wcat, ushort_t* __restrict__ Ww,
                     float* __restrict__ bias_cat) {
  if (blockIdx.x < 16384) {
    size_t i = ((size_t)blockIdx.x * 256 + threadIdx.x) * 4;
    float4 f = *(const float4*)(v + i);
    unsigned lo = (unsigned)f2bf(f.x) | (((unsigned)f2bf(f.y)) << 16);
    unsigned hi = (unsigned)f2bf(f.z) | (((unsigned)f2bf(f.w)) << 16);
    *(uint2*)(vbf + i) = make_uint2(lo, hi);
  } else {
    int i = (blockIdx.x - 16384) * 256 + threadIdx.x;
    if (i < 1536 * 1024) {
      int r = i >> 10;
      float val;
      if (r < 512)        val = g_w[i];
      else if (r < 1024)  val = th_w[i - 512 * 1024];
      else                val = ph_w[i - 1024 * 1024];
      Wcat[i] = f2bf(val);
    } else {
      int j = i - 1536 * 1024;
      Ww[j] = f2bf(W_w[j]);   // W_w is (1024, 512) row-major == B^T layout
    }
    if (i < 512)        bias_cat[i] = g_b[i];
    else if (i < 1024)  bias_cat[i] = th_b[i - 512];
    else if (i < 1536)  bias_cat[i] = ph_b[i - 1024];
  }
}

// ---------------- GEMM1: P-projections with layout-split epilogue -------------------
// A = vbf (16384x1024), B = Wcat^T (1536x1024). Output column ranges:
//   [0,512)     -> gvT[b][c][n]       (transposed; LDS-bounce coalesced)
//   [512,1024)  -> th[n][c-512]       (row-major, ld=512)
//   [1024,1536) -> phT[b][c-1024][n]  (transposed; LDS-bounce coalesced)
__global__ __launch_bounds__(256) void gemm1(
    const ushort_t* __restrict__ A, const ushort_t* __restrict__ B,
    ushort_t* __restrict__ gvT, ushort_t* __restrict__ th, ushort_t* __restrict__ phT,
    const float* __restrict__ bias) {
  constexpr int BM = 128, BN = 128, FR_M = 4, FR_N = 4;
  __shared__ ushort_t sh[BM * 64 + BN * 64];   // As | Bs ; aliased as Tt in epilogue
  ushort_t* As = sh;
  ushort_t* Bs = sh + BM * 64;
  const int tid = threadIdx.x;
  const int lane = tid & 63;
  const int wm = tid >> 7;
  const int wn = (tid >> 6) & 1;
  const int tm0 = blockIdx.x * BM, tn0 = blockIdx.y * BN;

  f32x4 acc[FR_M][FR_N] = {};

  for (int kt = 0; kt < 1024; kt += 64) {
#pragma unroll
    for (int it = 0; it < 4; ++it) {
      int g = it * 256 + tid;
      gload_lds16(A + (long)(tm0 + (g >> 3)) * 1024 + kt + (g & 7) * 8, &As[g * 8]);
    }
#pragma unroll
    for (int it = 0; it < 4; ++it) {
      int g = it * 256 + tid;
      gload_lds16(B + (long)(tn0 + (g >> 3)) * 1024 + kt + (g & 7) * 8, &Bs[g * 8]);
    }
    __syncthreads();
#pragma unroll
    for (int kk = 0; kk < 2; ++kk) {
      bf16x8 af[FR_M], bfr[FR_N];
#pragma unroll
      for (int m = 0; m < FR_M; ++m)
        af[m] = *(const bf16x8*)&As[(wm * 64 + m * 16 + (lane & 15)) * 64 +
                                    kk * 32 + (lane >> 4) * 8];
#pragma unroll
      for (int n = 0; n < FR_N; ++n)
        bfr[n] = *(const bf16x8*)&Bs[(wn * 64 + n * 16 + (lane & 15)) * 64 +
                                     kk * 32 + (lane >> 4) * 8];
#pragma unroll
      for (int m = 0; m < FR_M; ++m)
#pragma unroll
        for (int n = 0; n < FR_N; ++n)
          acc[m][n] = __builtin_amdgcn_mfma_f32_16x16x32_bf16(af[m], bfr[n], acc[m][n], 0, 0, 0);
    }
    __syncthreads();
  }

  if (tn0 >= 512 && tn0 < 1024) {
    // th: row-major direct store (32B segments per 16-lane group, merges across n)
#pragma unroll
    for (int n = 0; n < FR_N; ++n) {
      const int gcol = tn0 + wn * 64 + n * 16 + (lane & 15);
      const float bv = bias[gcol];
      const int col = gcol - 512;
#pragma unroll
      for (int m = 0; m < FR_M; ++m) {
#pragma unroll
        for (int r = 0; r < 4; ++r) {
          const int row = tm0 + wm * 64 + m * 16 + (lane >> 4) * 4 + r;
          th[(size_t)row * 512 + col] = f2bf(acc[m][n][r] + bv);
        }
      }
    }
  } else {
    // transposed outputs via LDS bounce: two passes of 64 columns each.
    ushort_t* T = (tn0 < 512) ? gvT : phT;
    const int coff = (tn0 < 512) ? 0 : 1024;
    const int cbase = tn0 - coff;              // 0,128,256,384
    const int bq = tm0 >> 12;                  // batch (tiles never straddle 4096)
    const int npb = tm0 & 4095;
    ushort_t* Tt = sh;                          // 64*136 = 8704 el <= 16384
#pragma unroll
    for (int p = 0; p < 2; ++p) {
      __syncthreads();   // sh free (post k-loop barrier / previous pass readout)
#pragma unroll
      for (int q = 0; q < 2; ++q) {
        const int n = 2 * p + q;
        const float bv = bias[tn0 + wn * 64 + n * 16 + (lane & 15)];
        const int lc = wn * 32 + q * 16 + (lane & 15);
#pragma unroll
        for (int m = 0; m < FR_M; ++m) {
          const int lrow = wm * 64 + m * 16 + (lane >> 4) * 4;
          unsigned lo = (unsigned)f2bf(acc[m][n][0] + bv) |
                        (((unsigned)f2bf(acc[m][n][1] + bv)) << 16);
          unsigned hi = (unsigned)f2bf(acc[m][n][2] + bv) |
                        (((unsigned)f2bf(acc[m][n][3] + bv)) << 16);
          *(uint2*)&Tt[lc * 136 + lrow] = make_uint2(lo, hi);
        }
      }
      __syncthreads();
      // writeout: 64 cols x 128 rows; 16 lanes cover 256B contiguous per col
#pragma unroll
      for (int s = 0; s < 4; ++s) {
        const int lc = (tid >> 4) + s * 16;
        const int seg = tid & 15;
        bf16x8 val = *(const bf16x8*)&Tt[lc * 136 + seg * 8];
        const int colc = cbase + (lc >> 5) * 64 + p * 32 + (lc & 31);
        *(bf16x8*)(T + ((size_t)(bq * 512 + colc)) * 4096 + npb + seg * 8) = val;
      }
    }
  }
}

// ---------------- bf16 GEMM: C[m][n] = alpha * sum_k A[m][k]*BT[n][k] (+ bias[n]) ---
template <int BM, int BN, bool BIAS, bool STATS>
__global__ __launch_bounds__(256) void gemm_bt(
    const ushort_t* __restrict__ A, const ushort_t* __restrict__ B,
    ushort_t* __restrict__ C, const float* __restrict__ bias,
    int K, int lda, int ldb, int ldc, long sA, long sB, long sC, float alpha,
    float* __restrict__ stats_out) {
  constexpr int FR_M = BM / 32, FR_N = BN / 32;
  __shared__ ushort_t As[BM * 64];
  __shared__ ushort_t Bs[BN * 64];
  const int tid = threadIdx.x;
  const int lane = tid & 63;
  const int wm = tid >> 7;
  const int wn = (tid >> 6) & 1;
  const long b = blockIdx.z;
  A += b * sA; B += b * sB; C += b * sC;
  const int tm0 = blockIdx.x * BM, tn0 = blockIdx.y * BN;

  f32x4 acc[FR_M][FR_N] = {};

  for (int kt = 0; kt < K; kt += 64) {
#pragma unroll
    for (int it = 0; it < BM / 32; ++it) {
      int g = it * 256 + tid;
      gload_lds16(A + (long)(tm0 + (g >> 3)) * lda + kt + (g & 7) * 8, &As[g * 8]);
    }
#pragma unroll
    for (int it = 0; it < BN / 32; ++it) {
      int g = it * 256 + tid;
      gload_lds16(B + (long)(tn0 + (g >> 3)) * ldb + kt + (g & 7) * 8, &Bs[g * 8]);
    }
    __syncthreads();
#pragma unroll
    for (int kk = 0; kk < 2; ++kk) {
      bf16x8 af[FR_M], bfr[FR_N];
#pragma unroll
      for (int m = 0; m < FR_M; ++m)
        af[m] = *(const bf16x8*)&As[(wm * (BM / 2) + m * 16 + (lane & 15)) * 64 +
                                    kk * 32 + (lane >> 4) * 8];
#pragma unroll
      for (int n = 0; n < FR_N; ++n)
        bfr[n] = *(const bf16x8*)&Bs[(wn * (BN / 2) + n * 16 + (lane & 15)) * 64 +
                                     kk * 32 + (lane >> 4) * 8];
#pragma unroll
      for (int m = 0; m < FR_M; ++m)
#pragma unroll
        for (int n = 0; n < FR_N; ++n)
          acc[m][n] = __builtin_amdgcn_mfma_f32_16x16x32_bf16(af[m], bfr[n], acc[m][n], 0, 0, 0);
    }
    __syncthreads();
  }

#pragma unroll
  for (int n = 0; n < FR_N; ++n) {
    const int col = tn0 + wn * (BN / 2) + n * 16 + (lane & 15);
    const float bv = BIAS ? bias[col] : 0.0f;
    float s = 0.f, s2 = 0.f;
#pragma unroll
    for (int m = 0; m < FR_M; ++m) {
#pragma unroll
      for (int r = 0; r < 4; ++r) {
        const int row = tm0 + wm * (BM / 2) + m * 16 + (lane >> 4) * 4 + r;
        float val = alpha * acc[m][n][r] + bv;
        C[(long)row * ldc + col] = f2bf(val);
        if (STATS) { s += val; s2 += val * val; }
      }
    }
    if (STATS) {
      s  += __shfl_xor(s, 16);  s  += __shfl_xor(s, 32);
      s2 += __shfl_xor(s2, 16); s2 += __shfl_xor(s2, 32);
      if ((lane >> 4) == 0) {
        atomicAdd(&stats_out[col], s);
        atomicAdd(&stats_out[1024 + col], s2);
      }
    }
  }
}

// ---------------- split-K GEMM2: Mpart[b*4+kc][i][j] (fp32, pre-scaled 1/4096) ------
__global__ __launch_bounds__(256) void gemm_splitk(
    const ushort_t* __restrict__ A, const ushort_t* __restrict__ B,
    float* __restrict__ Cp) {
  constexpr int BM = 128, BN = 64, FR_M = 4, FR_N = 2;
  __shared__ ushort_t As[BM * 64];
  __shared__ ushort_t Bs[BN * 64];
  const int tid = threadIdx.x;
  const int lane = tid & 63;
  const int wm = tid >> 7;
  const int wn = (tid >> 6) & 1;
  const int b = blockIdx.z >> 2, kc = blockIdx.z & 3;
  const ushort_t* Ab = A + (size_t)b * 512 * 4096 + kc * 1024;
  const ushort_t* Bb = B + (size_t)b * 512 * 4096 + kc * 1024;
  float* Cb = Cp + (size_t)blockIdx.z * 512 * 512;
  const int tm0 = blockIdx.x * BM, tn0 = blockIdx.y * BN;

  f32x4 acc[FR_M][FR_N] = {};

  for (int kt = 0; kt < 1024; kt += 64) {
#pragma unroll
    for (int it = 0; it < BM / 32; ++it) {
      int g = it * 256 + tid;
      gload_lds16(Ab + (long)(tm0 + (g >> 3)) * 4096 + kt + (g & 7) * 8, &As[g * 8]);
    }
#pragma unroll
    for (int it = 0; it < BN / 32; ++it) {
      int g = it * 256 + tid;
      gload_lds16(Bb + (long)(tn0 + (g >> 3)) * 4096 + kt + (g & 7) * 8, &Bs[g * 8]);
    }
    __syncthreads();
#pragma unroll
    for (int kk = 0; kk < 2; ++kk) {
      bf16x8 af[FR_M], bfr[FR_N];
#pragma unroll
      for (int m = 0; m < FR_M; ++m)
        af[m] = *(const bf16x8*)&As[(wm * (BM / 2) + m * 16 + (lane & 15)) * 64 +
                                    kk * 32 + (lane >> 4) * 8];
#pragma unroll
      for (int n = 0; n < FR_N; ++n)
        bfr[n] = *(const bf16x8*)&Bs[(wn * (BN / 2) + n * 16 + (lane & 15)) * 64 +
                                     kk * 32 + (lane >> 4) * 8];
#pragma unroll
      for (int m = 0; m < FR_M; ++m)
#pragma unroll
        for (int n = 0; n < FR_N; ++n)
          acc[m][n] = __builtin_amdgcn_mfma_f32_16x16x32_bf16(af[m], bfr[n], acc[m][n], 0, 0, 0);
    }
    __syncthreads();
  }

#pragma unroll
  for (int m = 0; m < FR_M; ++m)
#pragma unroll
    for (int n = 0; n < FR_N; ++n) {
      const int col = tn0 + wn * (BN / 2) + n * 16 + (lane & 15);
#pragma unroll
      for (int r = 0; r < 4; ++r) {
        const int row = tm0 + wm * (BM / 2) + m * 16 + (lane >> 4) * 4 + r;
        Cb[(long)row * 512 + col] = (1.0f / 4096.0f) * acc[m][n][r];
      }
    }
}

// ---------------- reduce 4 K-partials -> Mb bf16 [b][i][j] --------------------------
__global__ void reduce_cast_m(const float* __restrict__ Mpart, ushort_t* __restrict__ Mb) {
  int i = blockIdx.x * 256 + threadIdx.x;
  int b = i >> 16;
  int off = i & 65535;
  const float4* base = (const float4*)Mpart;
  float4 s  = base[(size_t)(b * 4 + 0) * 65536 + off];
  float4 t1 = base[(size_t)(b * 4 + 1) * 65536 + off];
  float4 t2 = base[(size_t)(b * 4 + 2) * 65536 + off];
  float4 t3 = base[(size_t)(b * 4 + 3) * 65536 + off];
  s.x += t1.x + t2.x + t3.x;
  s.y += t1.y + t2.y + t3.y;
  s.z += t1.z + t2.z + t3.z;
  s.w += t1.w + t2.w + t3.w;
  unsigned lo = (unsigned)f2bf(s.x) | (((unsigned)f2bf(s.y)) << 16);
  unsigned hi = (unsigned)f2bf(s.z) | (((unsigned)f2bf(s.w)) << 16);
  *(uint2*)(Mb + (size_t)i * 4) = make_uint2(lo, hi);
}

__global__ void bn_finalize(const float* __restrict__ sums, const float* __restrict__ gamma,
                            const float* __restrict__ beta, float* __restrict__ scsh) {
  int c = blockIdx.x * 256 + threadIdx.x;
  float mean = sums[c] * (1.0f / 16384.0f);
  float var = sums[1024 + c] * (1.0f / 16384.0f) - mean * mean;
  float sc = gamma[c] * rsqrtf(var + 1e-5f);
  scsh[c] = sc;
  scsh[1024 + c] = beta[c] - mean * sc;
}

// ---------------- apply BN + residual: out = Wy*scale + shift + v (bf16 v) ----------
__global__ void bn_apply(const ushort_t* __restrict__ Wy, const ushort_t* __restrict__ vbf,
                         const float* __restrict__ scsh, float* __restrict__ out) {
  size_t i = ((size_t)blockIdx.x * 256 + threadIdx.x) * 8;
  int c0 = (int)(i & 1023);
  bf16x8 w = *(const bf16x8*)(Wy + i);
  bf16x8 vv = *(const bf16x8*)(vbf + i);
  float4 sc0 = *(const float4*)(scsh + c0);
  float4 sc1 = *(const float4*)(scsh + c0 + 4);
  float4 sh0 = *(const float4*)(scsh + 1024 + c0);
  float4 sh1 = *(const float4*)(scsh + 1024 + c0 + 4);
  float4 o0, o1;
  o0.x = bf2f((unsigned short)w[0]) * sc0.x + sh0.x + bf2f((unsigned short)vv[0]);
  o0.y = bf2f((unsigned short)w[1]) * sc0.y + sh0.y + bf2f((unsigned short)vv[1]);
  o0.z = bf2f((unsigned short)w[2]) * sc0.z + sh0.z + bf2f((unsigned short)vv[2]);
  o0.w = bf2f((unsigned short)w[3]) * sc0.w + sh0.w + bf2f((unsigned short)vv[3]);
  o1.x = bf2f((unsigned short)w[4]) * sc1.x + sh1.x + bf2f((unsigned short)vv[4]);
  o1.y = bf2f((unsigned short)w[5]) * sc1.y + sh1.y + bf2f((unsigned short)vv[5]);
  o1.z = bf2f((unsigned short)w[6]) * sc1.z + sh1.z + bf2f((unsigned short)vv[6]);
  o1.w = bf2f((unsigned short)w[7]) * sc1.w + sh1.w + bf2f((unsigned short)vv[7]);
  *(float4*)(out + i) = o0;
  *(float4*)(out + i + 4) = o1;
}

extern "C" void kernel_launch(void* const* d_in, const int* in_sizes, int n_in,
                              void* d_out, int out_size, void* d_ws, size_t ws_size,
                              hipStream_t stream) {
  const float* v     = (const float*)d_in[0];
  const float* g_w   = (const float*)d_in[1];
  const float* g_b   = (const float*)d_in[2];
  const float* th_w  = (const float*)d_in[3];
  const float* th_b  = (const float*)d_in[4];
  const float* ph_w  = (const float*)d_in[5];
  const float* ph_b  = (const float*)d_in[6];
  const float* W_w   = (const float*)d_in[7];
  const float* W_b   = (const float*)d_in[8];
  const float* gamma = (const float*)d_in[9];
  const float* beta  = (const float*)d_in[10];
  float* out = (float*)d_out;
  char* ws = (char*)d_ws;

  const size_t MB = 1024 * 1024;
  // Lifetime-packed plan (max 107 MB):
  //  [0,32)   vbf          prep -> gemm1, bn_apply
  //  [32,48)  th           gemm1 -> gemm3'
  //  [48,64)  gvT          gemm1 -> splitk   }  overlaid by Wy after splitk
  //  [64,80)  phT          gemm1 -> splitk   }
  //  [80,96)  Mpart        splitk -> reduce
  //  [96,98)  Mb, [98,102) Qb, [102,105) Wcat, [105,106) Wwb, [106,...) misc
  ushort_t* vbf   = (ushort_t*)(ws);
  ushort_t* th    = (ushort_t*)(ws + 32 * MB);
  ushort_t* gvT   = (ushort_t*)(ws + 48 * MB);
  ushort_t* phT   = (ushort_t*)(ws + 64 * MB);
  ushort_t* Wy    = (ushort_t*)(ws + 48 * MB);
  float*    Mpart = (float*)(ws + 80 * MB);
  ushort_t* Mb    = (ushort_t*)(ws + 96 * MB);
  ushort_t* Qb    = (ushort_t*)(ws + 98 * MB);
  ushort_t* Wcat  = (ushort_t*)(ws + 102 * MB);
  ushort_t* Wwb   = (ushort_t*)(ws + 105 * MB);
  float* biasc    = (float*)(ws + 106 * MB);
  float* stats    = (float*)(ws + 106 * MB + 64 * 1024);
  float* scsh     = (float*)(ws + 106 * MB + 128 * 1024);

  (void)hipMemsetAsync(stats, 0, 2048 * sizeof(float), stream);
  prep<<<24576, 256, 0, stream>>>(v, g_w, th_w, ph_w, W_w, g_b, th_b, ph_b,
                                  vbf, Wcat, Wwb, biasc);

  // GEMM1: projections; gv/ph written transposed via LDS bounce, th row-major
  gemm1<<<dim3(128, 12), 256, 0, stream>>>(vbf, Wcat, gvT, th, phT, biasc);

  // GEMM2 split-K: M~[i][j] = (1/4096) sum_n ph[n][i] gv[n][j]  (fp32 partials)
  gemm_splitk<<<dim3(4, 8, 16), 256, 0, stream>>>(phT, gvT, Mpart);
  reduce_cast_m<<<1024, 256, 0, stream>>>(Mpart, Mb);

  // Q-GEMM: Q[c][i] = sum_k Ww[c][k] * M~[i][k]
  gemm_bt<64, 64, false, false><<<dim3(16, 8, 4), 256, 0, stream>>>(
      Wwb, Mb, Qb, nullptr, 512, 512, 512, 512,
      0, 512L * 512, 1024L * 512, 1.0f, nullptr);

  // GEMM3': Wy[n][c] = sum_j th[n][j] * Q[c][j] + W_b[c]  (+fused BN stats)
  gemm_bt<128, 128, true, true><<<dim3(32, 8, 4), 256, 0, stream>>>(
      th, Qb, Wy, W_b, 512, 512, 512, 1024,
      4096L * 512, 1024L * 512, 4096L * 1024, 1.0f, stats);

  bn_finalize<<<4, 256, 0, stream>>>(stats, gamma, beta, scsh);
  bn_apply<<<8192, 256, 0, stream>>>(Wy, vbf, scsh, out);
}